// Round 1
// baseline (1093.043 us; speedup 1.0000x reference)
//
#include <hip/hip_runtime.h>
#include <stdint.h>

#define NN 50000
#define EE 800000
#define DH 128
#define NC 40
#define KCAT (14*DH)   // 1792
#define CAP 64         // ELL capacity; deg ~ Binom(800k,1/50k), P(deg>64) ~ 1e-18

typedef __bf16 bf16x8 __attribute__((ext_vector_type(8)));
typedef float floatx4 __attribute__((ext_vector_type(4)));

__device__ __forceinline__ float bf2f(unsigned short u) {
  union { uint32_t i; float f; } v; v.i = ((uint32_t)u) << 16; return v.f;
}
__device__ __forceinline__ unsigned short f2bf(float f) {
  union { float f; uint32_t i; } v; v.f = f;
  uint32_t x = v.i;
  uint32_t r = (x + 0x7fffu + ((x >> 16) & 1u)) >> 16;  // RNE
  return (unsigned short)r;
}

// ---------------- setup: zero ELL counts + dtype detect (merged) ----------------
__global__ void init_counts_detect(int* counts, const unsigned short* xw) {
  int i = blockIdx.x * blockDim.x + threadIdx.x;
  if (i < NN) counts[i] = 0;
  if (blockIdx.x == 0) {
    int t = threadIdx.x;
    int wild = 0;
    for (int k = t; k < 4096; k += 256) {
      unsigned e = (xw[k] >> 7) & 0xFF;
      if (e >= 0x90) wild++;
    }
    __shared__ int red[256];
    red[t] = wild;
    __syncthreads();
    for (int s = 128; s > 0; s >>= 1) {
      if (t < s) red[t] += red[t + s];
      __syncthreads();
    }
    if (t == 0) counts[NN] = red[0];  // flag slot
  }
}

// vectorized dtype convert (n must be divisible by 4)
__global__ void convert_f4(const void* in, unsigned short* outp, int n4, const int* flag) {
  bool isf32 = (*flag) > 32;
  for (int i = blockIdx.x * blockDim.x + threadIdx.x; i < n4;
       i += gridDim.x * blockDim.x) {
    ushort4 o;
    if (isf32) {
      float4 v = ((const float4*)in)[i];
      o.x = f2bf(v.x); o.y = f2bf(v.y); o.z = f2bf(v.z); o.w = f2bf(v.w);
    } else {
      o = ((const ushort4*)in)[i];
    }
    ((ushort4*)outp)[i] = o;
  }
}

// all four bias vectors in one launch; bb layout: b0[128] b1[128] bm[1664] b15[40]
__global__ void convert_bias(const void* b0, const void* b1, const void* bm,
                             const void* b15, unsigned short* bb, const int* flag) {
  bool isf32 = (*flag) > 32;
  int i = blockIdx.x * blockDim.x + threadIdx.x;
  if (i >= 1960) return;
  const void* src; int off;
  if (i < 128)        { src = b0;  off = i; }
  else if (i < 256)   { src = b1;  off = i - 128; }
  else if (i < 1920)  { src = bm;  off = i - 256; }
  else                { src = b15; off = i - 1920; }
  bb[i] = isf32 ? f2bf(((const float*)src)[off]) : ((const unsigned short*)src)[off];
}

// B[L][K][M] -> BT[L][Mpad][K] (bf16 out), zero-pad n>=M
__global__ void transpose_w(const void* B, unsigned short* BT,
                            int L, int K, int M, int Mpad, const int* flag) {
  bool isf32 = (*flag) > 32;
  int total = L * Mpad * K;
  for (int idx = blockIdx.x * blockDim.x + threadIdx.x; idx < total;
       idx += gridDim.x * blockDim.x) {
    int k = idx % K;
    int n = (idx / K) % Mpad;
    int l = idx / (K * Mpad);
    unsigned short v = 0;
    if (n < M) {
      size_t si = (size_t)l * K * M + (size_t)k * M + n;
      v = isf32 ? f2bf(((const float*)B)[si]) : ((const unsigned short*)B)[si];
    }
    BT[idx] = v;
  }
}

// ---------------- ELL adjacency build ----------------
__global__ void build_ell(const int* __restrict__ src, const int* __restrict__ dst,
                          const void* __restrict__ w,
                          int* __restrict__ cnt, int2* __restrict__ ell,
                          const int* __restrict__ flag) {
  bool isf32 = (*flag) > 32;
  int e = blockIdx.x * blockDim.x + threadIdx.x;
  if (e >= EE) return;
  int d = dst[e];
  if ((unsigned)d >= NN) return;
  int p = atomicAdd(&cnt[d], 1);
  if (p >= CAP) return;
  int s = src[e];
  float wf = isf32 ? ((const float*)w)[e] : bf2f(((const unsigned short*)w)[e]);
  if ((unsigned)s >= NN) { s = 0; wf = 0.f; }
  union { float f; int i; } wv; wv.f = wf;
  ell[(size_t)d * CAP + p] = make_int2(s, wv.i);
}

// ---------------- GEMM: C[N,128] = A[N,K] @ B[K,128] (+bias) ----------------
// Direct-to-register MFMA: no LDS, no barriers. 64 rows/block (grid 782),
// 4 waves each covering 64 rows x 32 cols. Fragment loads are 16 rows x 64B
// contiguous per instruction (fully 64B-coalesced); B is L2-resident; A rows
// shared by the 4 waves via L1. K templated (128/256) -> fully unrolled.
template <int K>
__global__ __launch_bounds__(256) void gemm_direct(
    const unsigned short* __restrict__ A, int lda,
    const unsigned short* __restrict__ BT,            // [128][K]
    unsigned short* __restrict__ C, int ldc,
    const unsigned short* __restrict__ bias) {
  int t = threadIdx.x;
  int wave = t >> 6, lane = t & 63;
  int q = lane >> 4, mn = lane & 15;
  int r0 = blockIdx.x * 64;
  int wcol = wave * 32;

  const unsigned short* ap[4];
  #pragma unroll
  for (int i = 0; i < 4; ++i) {
    int r = r0 + i * 16 + mn;
    if (r >= NN) r = NN - 1;            // clamp (stores are guarded)
    ap[i] = A + (size_t)r * lda + q * 8;
  }
  const unsigned short* bp[2];
  #pragma unroll
  for (int j = 0; j < 2; ++j) bp[j] = BT + (size_t)(wcol + j * 16 + mn) * K + q * 8;

  floatx4 acc[4][2];
  floatx4 zf = {0.f, 0.f, 0.f, 0.f};
  #pragma unroll
  for (int i = 0; i < 4; ++i)
    #pragma unroll
    for (int j = 0; j < 2; ++j) acc[i][j] = zf;

  #pragma unroll
  for (int kc = 0; kc < K; kc += 64) {
    bf16x8 fa[4][2], fb[2][2];
    #pragma unroll
    for (int i = 0; i < 4; ++i)
      #pragma unroll
      for (int ks = 0; ks < 2; ++ks)
        fa[i][ks] = *(const bf16x8*)(ap[i] + kc + ks * 32);
    #pragma unroll
    for (int j = 0; j < 2; ++j)
      #pragma unroll
      for (int ks = 0; ks < 2; ++ks)
        fb[j][ks] = *(const bf16x8*)(bp[j] + kc + ks * 32);
    #pragma unroll
    for (int ks = 0; ks < 2; ++ks)
      #pragma unroll
      for (int i = 0; i < 4; ++i)
        #pragma unroll
        for (int j = 0; j < 2; ++j)
          acc[i][j] = __builtin_amdgcn_mfma_f32_16x16x32_bf16(fa[i][ks], fb[j][ks],
                                                              acc[i][j], 0, 0, 0);
  }

  // C/D layout: col = lane&15, row = (lane>>4)*4 + reg
  #pragma unroll
  for (int j = 0; j < 2; ++j) {
    int col = wcol + j * 16 + mn;
    float badd = bias ? bf2f(bias[col]) : 0.0f;
    #pragma unroll
    for (int i = 0; i < 4; ++i) {
      int rbase = r0 + i * 16 + q * 4;
      #pragma unroll
      for (int rr = 0; rr < 4; ++rr) {
        int row = rbase + rr;
        if (row < NN) C[(size_t)row * ldc + col] = f2bf(acc[i][j][rr] + badd);
      }
    }
  }
}

// ---------------- final GEMM: s15[N,40] = xcat[N,1792] @ W15 (fp32 out) ----------
// Same direct structure: wave = 16 rows x 48 cols, grid 782, ~8 waves/SIMD of
// pure streaming. 28 K-chunks of 64, 8 loads + 6 MFMAs each.
__global__ __launch_bounds__(256) void gemm_cat_direct(
    const unsigned short* __restrict__ A,             // xcat [N][1792]
    const unsigned short* __restrict__ BT,            // [48][1792]
    float* __restrict__ C) {
  int t = threadIdx.x;
  int wave = t >> 6, lane = t & 63;
  int q = lane >> 4, mn = lane & 15;
  int r0 = blockIdx.x * 64 + wave * 16;
  int ar = r0 + mn;
  if (ar >= NN) ar = NN - 1;
  const unsigned short* ap = A + (size_t)ar * KCAT + q * 8;
  const unsigned short* bp[3];
  #pragma unroll
  for (int j = 0; j < 3; ++j) bp[j] = BT + (size_t)(j * 16 + mn) * KCAT + q * 8;

  floatx4 acc[3];
  floatx4 zf = {0.f, 0.f, 0.f, 0.f};
  #pragma unroll
  for (int j = 0; j < 3; ++j) acc[j] = zf;

  #pragma unroll 2
  for (int kc = 0; kc < KCAT; kc += 64) {
    bf16x8 fa[2], fb[3][2];
    #pragma unroll
    for (int ks = 0; ks < 2; ++ks) fa[ks] = *(const bf16x8*)(ap + kc + ks * 32);
    #pragma unroll
    for (int j = 0; j < 3; ++j)
      #pragma unroll
      for (int ks = 0; ks < 2; ++ks)
        fb[j][ks] = *(const bf16x8*)(bp[j] + kc + ks * 32);
    #pragma unroll
    for (int ks = 0; ks < 2; ++ks)
      #pragma unroll
      for (int j = 0; j < 3; ++j)
        acc[j] = __builtin_amdgcn_mfma_f32_16x16x32_bf16(fa[ks], fb[j][ks], acc[j],
                                                         0, 0, 0);
  }

  #pragma unroll
  for (int j = 0; j < 3; ++j) {
    int col = j * 16 + mn;
    if (col < NC) {
      #pragma unroll
      for (int rr = 0; rr < 4; ++rr) {
        int row = r0 + q * 4 + rr;
        if (row < NN) C[(size_t)row * NC + col] = acc[j][rr];
      }
    }
  }
}

// ---------------- SPMM fused: out = relu(agg + b) + res ----------------
// One WAVE per row; lane covers features {2*lane, 2*lane+1} (packed uint).
// All <=64 ELL slots staged in registers with ONE dwordx2/lane, broadcast via shfl.
__global__ __launch_bounds__(256) void spmm_layer(
    const unsigned short* __restrict__ support, const int* __restrict__ cnt,
    const int2* __restrict__ ell, const unsigned short* __restrict__ bias,
    const unsigned short* __restrict__ res, int res_stride,
    unsigned short* __restrict__ out, int out_stride) {
  int wave = threadIdx.x >> 6, lane = threadIdx.x & 63;
  int row = blockIdx.x * 4 + wave;
  if (row >= NN) return;
  int n = cnt[row];
  if (n > CAP) n = CAP;
  int2 ev = ell[(size_t)row * CAP + lane];  // lane j holds edge j
  float a0 = 0.f, a1 = 0.f;
  int j = 0;
  for (; j + 16 <= n; j += 16) {
    uint32_t g[16];
    int sidx[16];
    #pragma unroll
    for (int u = 0; u < 16; ++u) sidx[u] = __shfl(ev.x, j + u);
    #pragma unroll
    for (int u = 0; u < 16; ++u)
      g[u] = *(const uint32_t*)(support + (size_t)sidx[u] * DH + 2 * lane);
    #pragma unroll
    for (int u = 0; u < 16; ++u) {
      union { int i; float f; } wv; wv.i = __shfl(ev.y, j + u);
      a0 += wv.f * bf2f((unsigned short)(g[u] & 0xffff));
      a1 += wv.f * bf2f((unsigned short)(g[u] >> 16));
    }
  }
  for (; j + 8 <= n; j += 8) {
    uint32_t g[8];
    int sidx[8];
    #pragma unroll
    for (int u = 0; u < 8; ++u) sidx[u] = __shfl(ev.x, j + u);
    #pragma unroll
    for (int u = 0; u < 8; ++u)
      g[u] = *(const uint32_t*)(support + (size_t)sidx[u] * DH + 2 * lane);
    #pragma unroll
    for (int u = 0; u < 8; ++u) {
      union { int i; float f; } wv; wv.i = __shfl(ev.y, j + u);
      a0 += wv.f * bf2f((unsigned short)(g[u] & 0xffff));
      a1 += wv.f * bf2f((unsigned short)(g[u] >> 16));
    }
  }
  for (; j < n; ++j) {
    int s = __shfl(ev.x, j);
    union { int i; float f; } wv; wv.i = __shfl(ev.y, j);
    uint32_t g = *(const uint32_t*)(support + (size_t)s * DH + 2 * lane);
    a0 += wv.f * bf2f((unsigned short)(g & 0xffff));
    a1 += wv.f * bf2f((unsigned short)(g >> 16));
  }
  uint32_t bw = *(const uint32_t*)(bias + 2 * lane);
  uint32_t rw = *(const uint32_t*)(res + (size_t)row * res_stride + 2 * lane);
  float v0 = fmaxf(a0 + bf2f((unsigned short)(bw & 0xffff)), 0.f) +
             bf2f((unsigned short)(rw & 0xffff));
  float v1 = fmaxf(a1 + bf2f((unsigned short)(bw >> 16)), 0.f) +
             bf2f((unsigned short)(rw >> 16));
  uint32_t o = (uint32_t)f2bf(v0) | ((uint32_t)f2bf(v1) << 16);
  *(uint32_t*)(out + (size_t)row * out_stride + 2 * lane) = o;
}

// ---------------- final SPMM (d=40) + bias + log_softmax -> FP32 output ----------------
__global__ __launch_bounds__(256) void spmm_softmax_out(
    const float* __restrict__ s15, const int* __restrict__ cnt,
    const int2* __restrict__ ell, const unsigned short* __restrict__ bias,
    float* __restrict__ out) {
  int wave = threadIdx.x >> 6, lane = threadIdx.x & 63;
  int row = blockIdx.x * 4 + wave;
  if (row >= NN) return;
  int n = cnt[row];
  if (n > CAP) n = CAP;
  int2 ev = ell[(size_t)row * CAP + lane];
  int fl = lane < NC ? lane : NC - 1;  // keep all 64 lanes convergent for shfl
  float acc = 0.f;
  int j = 0;
  for (; j + 4 <= n; j += 4) {
    float g[4];
    #pragma unroll
    for (int u = 0; u < 4; ++u) {
      int s = __shfl(ev.x, j + u);
      g[u] = s15[(size_t)s * NC + fl];
    }
    #pragma unroll
    for (int u = 0; u < 4; ++u) {
      union { int i; float f; } wv; wv.i = __shfl(ev.y, j + u);
      acc += wv.f * g[u];
    }
  }
  for (; j < n; ++j) {
    int s = __shfl(ev.x, j);
    union { int i; float f; } wv; wv.i = __shfl(ev.y, j);
    acc += wv.f * s15[(size_t)s * NC + fl];
  }
  acc += bf2f(bias[fl]);
  float v = (lane < NC) ? acc : -3.0e38f;
  float m = v;
  #pragma unroll
  for (int off = 32; off > 0; off >>= 1) m = fmaxf(m, __shfl_xor(m, off));
  float e = (lane < NC) ? expf(v - m) : 0.f;
  float sum = e;
  #pragma unroll
  for (int off = 32; off > 0; off >>= 1) sum += __shfl_xor(sum, off);
  if (lane < NC) out[(size_t)row * NC + lane] = v - m - logf(sum);
}

extern "C" void kernel_launch(void* const* d_in, const int* in_sizes, int n_in,
                              void* d_out, int out_size, void* d_ws, size_t ws_size,
                              hipStream_t stream) {
  const void* x   = d_in[0];
  const int* esrc = (const int*)d_in[1];
  const int* edst = (const int*)d_in[2];
  const void* ew  = d_in[3];
  const void* W0  = d_in[4];
  const void* b0  = d_in[5];
  const void* W1  = d_in[6];
  const void* b1  = d_in[7];
  const void* Wm  = d_in[8];
  const void* bm  = d_in[9];
  const void* W15 = d_in[10];
  const void* b15 = d_in[11];
  float* out = (float*)d_out;   // reference output dtype = float32

  char* ws = (char*)d_ws;
  size_t off = 0;
  auto alloc = [&](size_t bytes) -> void* {
    void* p = ws + off;
    off = (off + bytes + 255) & ~(size_t)255;
    return p;
  };
  unsigned short* xcat = (unsigned short*)alloc((size_t)NN * KCAT * 2);  // x14|...|x1
  unsigned short* xbf  = (unsigned short*)alloc((size_t)NN * 256 * 2);
  unsigned short* supp = (unsigned short*)alloc((size_t)NN * DH * 2);
  unsigned short* zbuf = (unsigned short*)alloc((size_t)NN * DH * 2);
  float* s15           = (float*)alloc((size_t)NN * NC * 4);
  int* counts          = (int*)alloc((size_t)(NN + 1) * 4);  // [NN] = dtype wild count
  int2* ell            = (int2*)alloc((size_t)NN * CAP * 8);
  unsigned short* W0T  = (unsigned short*)alloc((size_t)256 * 128 * 2);
  unsigned short* W1T  = (unsigned short*)alloc((size_t)256 * 128 * 2);
  unsigned short* WmT  = (unsigned short*)alloc((size_t)13 * 128 * 128 * 2);
  unsigned short* W15T = (unsigned short*)alloc((size_t)48 * 1792 * 2);
  unsigned short* bb   = (unsigned short*)alloc((size_t)(128 + 128 + 13 * 128 + 40) * 2);
  if (off > ws_size) return;  // signature: output stays zero
  int* flag = counts + NN;
  unsigned short* b0b  = bb;
  unsigned short* b1b  = bb + 128;
  unsigned short* bmb  = bb + 256;
  unsigned short* b15b = bb + 256 + 13 * 128;

  init_counts_detect<<<197, 256, 0, stream>>>(counts, (const unsigned short*)x);
  transpose_w<<<128, 256, 0, stream>>>(W0, W0T, 1, 256, 128, 128, flag);
  transpose_w<<<128, 256, 0, stream>>>(W1, W1T, 1, 256, 128, 128, flag);
  transpose_w<<<832, 256, 0, stream>>>(Wm, WmT, 13, 128, 128, 128, flag);
  transpose_w<<<336, 256, 0, stream>>>(W15, W15T, 1, 1792, 40, 48, flag);
  convert_f4<<<2048, 256, 0, stream>>>(x, xbf, NN * 256 / 4, flag);
  convert_bias<<<8, 256, 0, stream>>>(b0, b1, bm, b15, bb, flag);
  build_ell<<<3125, 256, 0, stream>>>(esrc, edst, ew, counts, ell, flag);

  int gb = (NN + 63) / 64;   // 782
  int sb = (NN + 3) / 4;     // 12500 (4 rows/block, wave per row)
  gemm_direct<256><<<gb, 256, 0, stream>>>(xbf, 256, W0T, zbuf, DH, b0b);    // z = x@W0+b0
  gemm_direct<256><<<gb, 256, 0, stream>>>(xbf, 256, W1T, supp, DH, nullptr); // supp = x@W1
  spmm_layer<<<sb, 256, 0, stream>>>(supp, counts, ell, b1b, zbuf, DH,
                                     xcat + 13 * DH, KCAT);                  // x1
  for (int l = 0; l < 13; ++l) {
    gemm_direct<128><<<gb, 256, 0, stream>>>(xcat + (13 - l) * DH, KCAT,
                                             WmT + l * 128 * 128, supp, DH, nullptr);
    spmm_layer<<<sb, 256, 0, stream>>>(supp, counts, ell, bmb + l * DH,
                                       xcat + (13 - l) * DH, KCAT,
                                       xcat + (12 - l) * DH, KCAT);
  }
  gemm_cat_direct<<<gb, 256, 0, stream>>>(xcat, W15T, s15);
  spmm_softmax_out<<<sb, 256, 0, stream>>>(s15, counts, ell, b15b, out);
}

// Round 2
// 1017.413 us; speedup vs baseline: 1.0743x; 1.0743x over previous
//
#include <hip/hip_runtime.h>
#include <stdint.h>

#define NN 50000
#define EE 800000
#define DH 128
#define NC 40
#define KCAT (14*DH)   // 1792
#define CAP 64         // ELL capacity; deg ~ Binom(800k,1/50k), P(deg>64) ~ 1e-18

typedef __bf16 bf16x8 __attribute__((ext_vector_type(8)));
typedef float floatx4 __attribute__((ext_vector_type(4)));

// async global->LDS, 16B per lane, linear dest (wave-uniform base + lane*16)
#define GLOAD_LDS16(gp, lp)                                                          \
  __builtin_amdgcn_global_load_lds(                                                  \
      (const __attribute__((address_space(1))) uint32_t*)(gp),                       \
      (__attribute__((address_space(3))) uint32_t*)(lp), 16, 0, 0)

__device__ __forceinline__ float bf2f(unsigned short u) {
  union { uint32_t i; float f; } v; v.i = ((uint32_t)u) << 16; return v.f;
}
__device__ __forceinline__ unsigned short f2bf(float f) {
  union { float f; uint32_t i; } v; v.f = f;
  uint32_t x = v.i;
  uint32_t r = (x + 0x7fffu + ((x >> 16) & 1u)) >> 16;  // RNE
  return (unsigned short)r;
}

// ---------------- setup: zero ELL counts + dtype detect (merged) ----------------
__global__ void init_counts_detect(int* counts, const unsigned short* xw) {
  int i = blockIdx.x * blockDim.x + threadIdx.x;
  if (i < NN) counts[i] = 0;
  if (blockIdx.x == 0) {
    int t = threadIdx.x;
    int wild = 0;
    for (int k = t; k < 4096; k += 256) {
      unsigned e = (xw[k] >> 7) & 0xFF;
      if (e >= 0x90) wild++;
    }
    __shared__ int red[256];
    red[t] = wild;
    __syncthreads();
    for (int s = 128; s > 0; s >>= 1) {
      if (t < s) red[t] += red[t + s];
      __syncthreads();
    }
    if (t == 0) counts[NN] = red[0];  // flag slot
  }
}

// vectorized dtype convert (n must be divisible by 4)
__global__ void convert_f4(const void* in, unsigned short* outp, int n4, const int* flag) {
  bool isf32 = (*flag) > 32;
  for (int i = blockIdx.x * blockDim.x + threadIdx.x; i < n4;
       i += gridDim.x * blockDim.x) {
    ushort4 o;
    if (isf32) {
      float4 v = ((const float4*)in)[i];
      o.x = f2bf(v.x); o.y = f2bf(v.y); o.z = f2bf(v.z); o.w = f2bf(v.w);
    } else {
      o = ((const ushort4*)in)[i];
    }
    ((ushort4*)outp)[i] = o;
  }
}

// all four bias vectors in one launch; bb layout: b0[128] b1[128] bm[1664] b15[40]
__global__ void convert_bias(const void* b0, const void* b1, const void* bm,
                             const void* b15, unsigned short* bb, const int* flag) {
  bool isf32 = (*flag) > 32;
  int i = blockIdx.x * blockDim.x + threadIdx.x;
  if (i >= 1960) return;
  const void* src; int off;
  if (i < 128)        { src = b0;  off = i; }
  else if (i < 256)   { src = b1;  off = i - 128; }
  else if (i < 1920)  { src = bm;  off = i - 256; }
  else                { src = b15; off = i - 1920; }
  bb[i] = isf32 ? f2bf(((const float*)src)[off]) : ((const unsigned short*)src)[off];
}

// B[L][K][M] -> BT[L][Mpad][K] (bf16 out), zero-pad n>=M
__global__ void transpose_w(const void* B, unsigned short* BT,
                            int L, int K, int M, int Mpad, const int* flag) {
  bool isf32 = (*flag) > 32;
  int total = L * Mpad * K;
  for (int idx = blockIdx.x * blockDim.x + threadIdx.x; idx < total;
       idx += gridDim.x * blockDim.x) {
    int k = idx % K;
    int n = (idx / K) % Mpad;
    int l = idx / (K * Mpad);
    unsigned short v = 0;
    if (n < M) {
      size_t si = (size_t)l * K * M + (size_t)k * M + n;
      v = isf32 ? f2bf(((const float*)B)[si]) : ((const unsigned short*)B)[si];
    }
    BT[idx] = v;
  }
}

// ---------------- ELL adjacency build ----------------
__global__ void build_ell(const int* __restrict__ src, const int* __restrict__ dst,
                          const void* __restrict__ w,
                          int* __restrict__ cnt, int2* __restrict__ ell,
                          const int* __restrict__ flag) {
  bool isf32 = (*flag) > 32;
  int e = blockIdx.x * blockDim.x + threadIdx.x;
  if (e >= EE) return;
  int d = dst[e];
  if ((unsigned)d >= NN) return;
  int p = atomicAdd(&cnt[d], 1);
  if (p >= CAP) return;
  int s = src[e];
  float wf = isf32 ? ((const float*)w)[e] : bf2f(((const unsigned short*)w)[e]);
  if ((unsigned)s >= NN) { s = 0; wf = 0.f; }
  union { float f; int i; } wv; wv.f = wf;
  ell[(size_t)d * CAP + p] = make_int2(s, wv.i);
}

// ============ first GEMM pair: z = x@W0+b0, supp = x@W1 (K=256, 256 cols) ============
// 64-row block, A staged ONCE via global_load_lds (swizzled), single barrier.
// B direct from global (128KB, L2-hot, fragment-shaped 16B reads).
__global__ __launch_bounds__(256) void gemm_first(
    const unsigned short* __restrict__ A,    // xbf [N][256]
    const unsigned short* __restrict__ BT,   // [256][256]: rows 0-127=W0T, 128-255=W1T
    unsigned short* __restrict__ C0,         // zbuf [N][128]  (+bias)
    unsigned short* __restrict__ C1,         // supp [N][128]
    const unsigned short* __restrict__ bias) {
  __shared__ unsigned short As[64 * 256];    // 32KB, row stride 512B, swizzled
  int t = threadIdx.x;
  int wave = t >> 6, lane = t & 63;
  int q = lane >> 4, mn = lane & 15;
  int r0 = blockIdx.x * 64;

  #pragma unroll
  for (int cc = 0; cc < 8; ++cc) {
    int L = cc * 4096 + t * 16;
    int row = L >> 9;
    int colb = (L & 511) ^ ((row & 7) << 4);
    int gr = r0 + row; if (gr >= NN) gr = NN - 1;
    GLOAD_LDS16((const char*)A + (size_t)gr * 512 + colb, (char*)As + L);
  }
  __syncthreads();

  floatx4 acc[4][4];
  floatx4 zf = {0.f, 0.f, 0.f, 0.f};
  #pragma unroll
  for (int i = 0; i < 4; ++i)
    #pragma unroll
    for (int j = 0; j < 4; ++j) acc[i][j] = zf;

  #pragma unroll
  for (int ks = 0; ks < 8; ++ks) {
    bf16x8 fa[4], fb[4];
    #pragma unroll
    for (int i = 0; i < 4; ++i) {
      int row = i * 16 + mn;
      fa[i] = *(const bf16x8*)((const char*)As + row * 512 +
                               ((ks * 64 + q * 16) ^ ((row & 7) << 4)));
    }
    #pragma unroll
    for (int j = 0; j < 4; ++j)
      fb[j] = *(const bf16x8*)((const char*)BT +
                               (size_t)(wave * 64 + j * 16 + mn) * 512 + ks * 64 + q * 16);
    #pragma unroll
    for (int i = 0; i < 4; ++i)
      #pragma unroll
      for (int j = 0; j < 4; ++j)
        acc[i][j] = __builtin_amdgcn_mfma_f32_16x16x32_bf16(fa[i], fb[j], acc[i][j], 0, 0, 0);
  }

  #pragma unroll
  for (int j = 0; j < 4; ++j) {
    int col = wave * 64 + j * 16 + mn;
    bool is0 = col < 128;
    int ccol = is0 ? col : col - 128;
    unsigned short* Cp = is0 ? C0 : C1;
    float badd = is0 ? bf2f(bias[ccol]) : 0.f;
    #pragma unroll
    for (int i = 0; i < 4; ++i) {
      int rbase = r0 + i * 16 + q * 4;
      #pragma unroll
      for (int rr = 0; rr < 4; ++rr) {
        int row = rbase + rr;
        if (row < NN) Cp[(size_t)row * 128 + ccol] = f2bf(acc[i][j][rr] + badd);
      }
    }
  }
}

// ============ mid GEMM: supp[N,128] = x_l[N(,KCAT stride)][128] @ B ============
// 32-row block (grid 1563, ~6 blocks/CU), A staged once, single barrier. B direct (32KB).
__global__ __launch_bounds__(256) void gemm_mid(
    const unsigned short* __restrict__ A,    // row stride KCAT
    const unsigned short* __restrict__ BT,   // [128][128]
    unsigned short* __restrict__ C) {        // supp [N][128]
  __shared__ unsigned short As[32 * 128];    // 8KB, row stride 256B, swizzled
  int t = threadIdx.x;
  int wave = t >> 6, lane = t & 63;
  int q = lane >> 4, mn = lane & 15;
  int r0 = blockIdx.x * 32;

  #pragma unroll
  for (int cc = 0; cc < 2; ++cc) {
    int L = cc * 4096 + t * 16;
    int row = L >> 8;
    int colb = (L & 255) ^ ((row & 7) << 4);
    int gr = r0 + row; if (gr >= NN) gr = NN - 1;
    GLOAD_LDS16((const char*)A + (size_t)gr * (KCAT * 2) + colb, (char*)As + L);
  }
  __syncthreads();

  floatx4 acc[2][2];
  floatx4 zf = {0.f, 0.f, 0.f, 0.f};
  #pragma unroll
  for (int i = 0; i < 2; ++i)
    #pragma unroll
    for (int j = 0; j < 2; ++j) acc[i][j] = zf;

  #pragma unroll
  for (int ks = 0; ks < 4; ++ks) {
    bf16x8 fa[2], fb[2];
    #pragma unroll
    for (int i = 0; i < 2; ++i) {
      int row = i * 16 + mn;
      fa[i] = *(const bf16x8*)((const char*)As + row * 256 +
                               ((ks * 64 + q * 16) ^ ((row & 7) << 4)));
    }
    #pragma unroll
    for (int j = 0; j < 2; ++j)
      fb[j] = *(const bf16x8*)((const char*)BT +
                               (size_t)(wave * 32 + j * 16 + mn) * 256 + ks * 64 + q * 16);
    #pragma unroll
    for (int i = 0; i < 2; ++i)
      #pragma unroll
      for (int j = 0; j < 2; ++j)
        acc[i][j] = __builtin_amdgcn_mfma_f32_16x16x32_bf16(fa[i], fb[j], acc[i][j], 0, 0, 0);
  }

  #pragma unroll
  for (int i = 0; i < 2; ++i) {
    int rbase = r0 + i * 16 + q * 4;
    #pragma unroll
    for (int j = 0; j < 2; ++j) {
      int col = wave * 32 + j * 16 + mn;
      #pragma unroll
      for (int rr = 0; rr < 4; ++rr) {
        int row = rbase + rr;
        if (row < NN) C[(size_t)row * 128 + col] = f2bf(acc[i][j][rr]);
      }
    }
  }
}

// ============ final GEMM: s15[N,40] = xcat[N,1792] @ W15 (fp32 out) ============
// 64-row block, BK=128 double-buffered A via global_load_lds (swizzled),
// ONE barrier per chunk (14 total). B direct from global (12KB hot window -> L1).
__global__ __launch_bounds__(256) void gemm_cat2(
    const unsigned short* __restrict__ A,    // xcat [N][1792]
    const unsigned short* __restrict__ BT,   // [48][1792]
    float* __restrict__ C) {
  __shared__ unsigned short As[2][64 * 128]; // 2 x 16KB, row stride 256B, swizzled
  int t = threadIdx.x;
  int wave = t >> 6, lane = t & 63;
  int q = lane >> 4, mn = lane & 15;
  int r0 = blockIdx.x * 64;

  floatx4 acc[3];
  floatx4 zf = {0.f, 0.f, 0.f, 0.f};
  #pragma unroll
  for (int j = 0; j < 3; ++j) acc[j] = zf;

  // stage chunk c (k-offset c*128) into As[c&1]
  auto stage = [&](int c) {
    #pragma unroll
    for (int cc = 0; cc < 4; ++cc) {
      int L = cc * 4096 + t * 16;
      int row = L >> 8;
      int colb = (L & 255) ^ ((row & 7) << 4);
      int gr = r0 + row; if (gr >= NN) gr = NN - 1;
      GLOAD_LDS16((const char*)A + (size_t)gr * 3584 + c * 256 + colb,
                  (char*)As[c & 1] + L);
    }
  };

  stage(0);
  __syncthreads();
  for (int c = 0; c < 14; ++c) {
    if (c + 1 < 14) stage(c + 1);      // loads overlap compute; drained at barrier
    const char* buf = (const char*)As[c & 1];
    int rloc = wave * 16 + mn;
    int rsw = (rloc & 7) << 4;
    #pragma unroll
    for (int ks = 0; ks < 4; ++ks) {
      bf16x8 fa = *(const bf16x8*)(buf + rloc * 256 + ((ks * 64 + q * 16) ^ rsw));
      bf16x8 fb[3];
      #pragma unroll
      for (int j = 0; j < 3; ++j)
        fb[j] = *(const bf16x8*)((const char*)BT + (size_t)(j * 16 + mn) * 3584 +
                                 c * 256 + ks * 64 + q * 16);
      #pragma unroll
      for (int j = 0; j < 3; ++j)
        acc[j] = __builtin_amdgcn_mfma_f32_16x16x32_bf16(fa, fb[j], acc[j], 0, 0, 0);
    }
    if (c + 1 < 14) __syncthreads();
  }

  #pragma unroll
  for (int j = 0; j < 3; ++j) {
    int col = j * 16 + mn;
    if (col < NC) {
      #pragma unroll
      for (int rr = 0; rr < 4; ++rr) {
        int row = r0 + wave * 16 + q * 4 + rr;
        if (row < NN) C[(size_t)row * NC + col] = acc[j][rr];
      }
    }
  }
}

// ---------------- SPMM fused: out = relu(agg + b) + res ----------------
__global__ __launch_bounds__(256) void spmm_layer(
    const unsigned short* __restrict__ support, const int* __restrict__ cnt,
    const int2* __restrict__ ell, const unsigned short* __restrict__ bias,
    const unsigned short* __restrict__ res, int res_stride,
    unsigned short* __restrict__ out, int out_stride) {
  int wave = threadIdx.x >> 6, lane = threadIdx.x & 63;
  int row = blockIdx.x * 4 + wave;
  if (row >= NN) return;
  int n = cnt[row];
  if (n > CAP) n = CAP;
  int2 ev = ell[(size_t)row * CAP + lane];  // lane j holds edge j
  float a0 = 0.f, a1 = 0.f;
  int j = 0;
  for (; j + 16 <= n; j += 16) {
    uint32_t g[16];
    int sidx[16];
    #pragma unroll
    for (int u = 0; u < 16; ++u) sidx[u] = __shfl(ev.x, j + u);
    #pragma unroll
    for (int u = 0; u < 16; ++u)
      g[u] = *(const uint32_t*)(support + (size_t)sidx[u] * DH + 2 * lane);
    #pragma unroll
    for (int u = 0; u < 16; ++u) {
      union { int i; float f; } wv; wv.i = __shfl(ev.y, j + u);
      a0 += wv.f * bf2f((unsigned short)(g[u] & 0xffff));
      a1 += wv.f * bf2f((unsigned short)(g[u] >> 16));
    }
  }
  for (; j + 8 <= n; j += 8) {
    uint32_t g[8];
    int sidx[8];
    #pragma unroll
    for (int u = 0; u < 8; ++u) sidx[u] = __shfl(ev.x, j + u);
    #pragma unroll
    for (int u = 0; u < 8; ++u)
      g[u] = *(const uint32_t*)(support + (size_t)sidx[u] * DH + 2 * lane);
    #pragma unroll
    for (int u = 0; u < 8; ++u) {
      union { int i; float f; } wv; wv.i = __shfl(ev.y, j + u);
      a0 += wv.f * bf2f((unsigned short)(g[u] & 0xffff));
      a1 += wv.f * bf2f((unsigned short)(g[u] >> 16));
    }
  }
  for (; j < n; ++j) {
    int s = __shfl(ev.x, j);
    union { int i; float f; } wv; wv.i = __shfl(ev.y, j);
    uint32_t g = *(const uint32_t*)(support + (size_t)s * DH + 2 * lane);
    a0 += wv.f * bf2f((unsigned short)(g & 0xffff));
    a1 += wv.f * bf2f((unsigned short)(g >> 16));
  }
  uint32_t bw = *(const uint32_t*)(bias + 2 * lane);
  uint32_t rw = *(const uint32_t*)(res + (size_t)row * res_stride + 2 * lane);
  float v0 = fmaxf(a0 + bf2f((unsigned short)(bw & 0xffff)), 0.f) +
             bf2f((unsigned short)(rw & 0xffff));
  float v1 = fmaxf(a1 + bf2f((unsigned short)(bw >> 16)), 0.f) +
             bf2f((unsigned short)(rw >> 16));
  uint32_t o = (uint32_t)f2bf(v0) | ((uint32_t)f2bf(v1) << 16);
  *(uint32_t*)(out + (size_t)row * out_stride + 2 * lane) = o;
}

// ---------------- final SPMM (d=40) + bias + log_softmax -> FP32 output ----------------
__global__ __launch_bounds__(256) void spmm_softmax_out(
    const float* __restrict__ s15, const int* __restrict__ cnt,
    const int2* __restrict__ ell, const unsigned short* __restrict__ bias,
    float* __restrict__ out) {
  int wave = threadIdx.x >> 6, lane = threadIdx.x & 63;
  int row = blockIdx.x * 4 + wave;
  if (row >= NN) return;
  int n = cnt[row];
  if (n > CAP) n = CAP;
  int2 ev = ell[(size_t)row * CAP + lane];
  int fl = lane < NC ? lane : NC - 1;  // keep all 64 lanes convergent for shfl
  float acc = 0.f;
  int j = 0;
  for (; j + 4 <= n; j += 4) {
    float g[4];
    #pragma unroll
    for (int u = 0; u < 4; ++u) {
      int s = __shfl(ev.x, j + u);
      g[u] = s15[(size_t)s * NC + fl];
    }
    #pragma unroll
    for (int u = 0; u < 4; ++u) {
      union { int i; float f; } wv; wv.i = __shfl(ev.y, j + u);
      acc += wv.f * g[u];
    }
  }
  for (; j < n; ++j) {
    int s = __shfl(ev.x, j);
    union { int i; float f; } wv; wv.i = __shfl(ev.y, j);
    acc += wv.f * s15[(size_t)s * NC + fl];
  }
  acc += bf2f(bias[fl]);
  float v = (lane < NC) ? acc : -3.0e38f;
  float m = v;
  #pragma unroll
  for (int off = 32; off > 0; off >>= 1) m = fmaxf(m, __shfl_xor(m, off));
  float e = (lane < NC) ? expf(v - m) : 0.f;
  float sum = e;
  #pragma unroll
  for (int off = 32; off > 0; off >>= 1) sum += __shfl_xor(sum, off);
  if (lane < NC) out[(size_t)row * NC + lane] = v - m - logf(sum);
}

extern "C" void kernel_launch(void* const* d_in, const int* in_sizes, int n_in,
                              void* d_out, int out_size, void* d_ws, size_t ws_size,
                              hipStream_t stream) {
  const void* x   = d_in[0];
  const int* esrc = (const int*)d_in[1];
  const int* edst = (const int*)d_in[2];
  const void* ew  = d_in[3];
  const void* W0  = d_in[4];
  const void* b0  = d_in[5];
  const void* W1  = d_in[6];
  const void* b1  = d_in[7];
  const void* Wm  = d_in[8];
  const void* bm  = d_in[9];
  const void* W15 = d_in[10];
  const void* b15 = d_in[11];
  float* out = (float*)d_out;   // reference output dtype = float32

  char* ws = (char*)d_ws;
  size_t off = 0;
  auto alloc = [&](size_t bytes) -> void* {
    void* p = ws + off;
    off = (off + bytes + 255) & ~(size_t)255;
    return p;
  };
  unsigned short* xcat = (unsigned short*)alloc((size_t)NN * KCAT * 2);  // x14|...|x1
  unsigned short* xbf  = (unsigned short*)alloc((size_t)NN * 256 * 2);
  unsigned short* supp = (unsigned short*)alloc((size_t)NN * DH * 2);
  unsigned short* zbuf = (unsigned short*)alloc((size_t)NN * DH * 2);
  float* s15           = (float*)alloc((size_t)NN * NC * 4);
  int* counts          = (int*)alloc((size_t)(NN + 1) * 4);  // [NN] = dtype wild count
  int2* ell            = (int2*)alloc((size_t)NN * CAP * 8);
  unsigned short* W01T = (unsigned short*)alloc((size_t)256 * 256 * 2);  // rows0-127=W0T,128-255=W1T
  unsigned short* WmT  = (unsigned short*)alloc((size_t)13 * 128 * 128 * 2);
  unsigned short* W15T = (unsigned short*)alloc((size_t)48 * 1792 * 2);
  unsigned short* bb   = (unsigned short*)alloc((size_t)(128 + 128 + 13 * 128 + 40) * 2);
  if (off > ws_size) return;  // signature: output stays zero
  int* flag = counts + NN;
  unsigned short* b0b  = bb;
  unsigned short* b1b  = bb + 128;
  unsigned short* bmb  = bb + 256;
  unsigned short* b15b = bb + 256 + 13 * 128;

  init_counts_detect<<<197, 256, 0, stream>>>(counts, (const unsigned short*)x);
  transpose_w<<<128, 256, 0, stream>>>(W0, W01T, 1, 256, 128, 128, flag);
  transpose_w<<<128, 256, 0, stream>>>(W1, W01T + 128 * 256, 1, 256, 128, 128, flag);
  transpose_w<<<832, 256, 0, stream>>>(Wm, WmT, 13, 128, 128, 128, flag);
  transpose_w<<<336, 256, 0, stream>>>(W15, W15T, 1, 1792, 40, 48, flag);
  convert_f4<<<2048, 256, 0, stream>>>(x, xbf, NN * 256 / 4, flag);
  convert_bias<<<8, 256, 0, stream>>>(b0, b1, bm, b15, bb, flag);
  build_ell<<<3125, 256, 0, stream>>>(esrc, edst, ew, counts, ell, flag);

  int gb64 = (NN + 63) / 64;   // 782
  int gb32 = (NN + 31) / 32;   // 1563
  int sb   = (NN + 3) / 4;     // 12500 (4 rows/block, wave per row)
  gemm_first<<<gb64, 256, 0, stream>>>(xbf, W01T, zbuf, supp, b0b);
  spmm_layer<<<sb, 256, 0, stream>>>(supp, counts, ell, b1b, zbuf, DH,
                                     xcat + 13 * DH, KCAT);                  // x1
  for (int l = 0; l < 13; ++l) {
    gemm_mid<<<gb32, 256, 0, stream>>>(xcat + (13 - l) * DH,
                                       WmT + l * 128 * 128, supp);
    spmm_layer<<<sb, 256, 0, stream>>>(supp, counts, ell, bmb + l * DH,
                                       xcat + (13 - l) * DH, KCAT,
                                       xcat + (12 - l) * DH, KCAT);
  }
  gemm_cat2<<<gb64, 256, 0, stream>>>(xcat, W15T, s15);
  spmm_softmax_out<<<sb, 256, 0, stream>>>(s15, counts, ell, b15b, out);
}

// Round 3
// 956.842 us; speedup vs baseline: 1.1423x; 1.0633x over previous
//
#include <hip/hip_runtime.h>
#include <stdint.h>

#define NN 50000
#define EE 800000
#define DH 128
#define NC 40
#define KCAT (14*DH)   // 1792
#define CAP 64         // ELL capacity; deg ~ Binom(800k,1/50k), P(deg>64) ~ 1e-18

typedef __bf16 bf16x8 __attribute__((ext_vector_type(8)));
typedef float floatx4 __attribute__((ext_vector_type(4)));

// async global->LDS, 16B per lane, linear dest (wave-uniform base + lane*16)
#define GLOAD_LDS16(gp, lp)                                                          \
  __builtin_amdgcn_global_load_lds(                                                  \
      (const __attribute__((address_space(1))) uint32_t*)(gp),                       \
      (__attribute__((address_space(3))) uint32_t*)(lp), 16, 0, 0)

__device__ __forceinline__ float bf2f(unsigned short u) {
  union { uint32_t i; float f; } v; v.i = ((uint32_t)u) << 16; return v.f;
}
__device__ __forceinline__ unsigned short f2bf(float f) {
  union { float f; uint32_t i; } v; v.f = f;
  uint32_t x = v.i;
  uint32_t r = (x + 0x7fffu + ((x >> 16) & 1u)) >> 16;  // RNE
  return (unsigned short)r;
}

// ---------------- setup: zero ELL counts + dtype detect (merged) ----------------
__global__ void init_counts_detect(int* counts, const unsigned short* xw) {
  int i = blockIdx.x * blockDim.x + threadIdx.x;
  if (i < NN) counts[i] = 0;
  if (blockIdx.x == 0) {
    int t = threadIdx.x;
    int wild = 0;
    for (int k = t; k < 4096; k += 256) {
      unsigned e = (xw[k] >> 7) & 0xFF;
      if (e >= 0x90) wild++;
    }
    __shared__ int red[256];
    red[t] = wild;
    __syncthreads();
    for (int s = 128; s > 0; s >>= 1) {
      if (t < s) red[t] += red[t + s];
      __syncthreads();
    }
    if (t == 0) counts[NN] = red[0];  // flag slot
  }
}

// vectorized dtype convert (n must be divisible by 4)
__global__ void convert_f4(const void* in, unsigned short* outp, int n4, const int* flag) {
  bool isf32 = (*flag) > 32;
  for (int i = blockIdx.x * blockDim.x + threadIdx.x; i < n4;
       i += gridDim.x * blockDim.x) {
    ushort4 o;
    if (isf32) {
      float4 v = ((const float4*)in)[i];
      o.x = f2bf(v.x); o.y = f2bf(v.y); o.z = f2bf(v.z); o.w = f2bf(v.w);
    } else {
      o = ((const ushort4*)in)[i];
    }
    ((ushort4*)outp)[i] = o;
  }
}

// all four bias vectors in one launch; bb layout: b0[128] b1[128] bm[1664] b15[40]
__global__ void convert_bias(const void* b0, const void* b1, const void* bm,
                             const void* b15, unsigned short* bb, const int* flag) {
  bool isf32 = (*flag) > 32;
  int i = blockIdx.x * blockDim.x + threadIdx.x;
  if (i >= 1960) return;
  const void* src; int off;
  if (i < 128)        { src = b0;  off = i; }
  else if (i < 256)   { src = b1;  off = i - 128; }
  else if (i < 1920)  { src = bm;  off = i - 256; }
  else                { src = b15; off = i - 1920; }
  bb[i] = isf32 ? f2bf(((const float*)src)[off]) : ((const unsigned short*)src)[off];
}

// B[L][K][M] -> BT[L][Mpad][K] (bf16 out), zero-pad n>=M
__global__ void transpose_w(const void* B, unsigned short* BT,
                            int L, int K, int M, int Mpad, const int* flag) {
  bool isf32 = (*flag) > 32;
  int total = L * Mpad * K;
  for (int idx = blockIdx.x * blockDim.x + threadIdx.x; idx < total;
       idx += gridDim.x * blockDim.x) {
    int k = idx % K;
    int n = (idx / K) % Mpad;
    int l = idx / (K * Mpad);
    unsigned short v = 0;
    if (n < M) {
      size_t si = (size_t)l * K * M + (size_t)k * M + n;
      v = isf32 ? f2bf(((const float*)B)[si]) : ((const unsigned short*)B)[si];
    }
    BT[idx] = v;
  }
}

// ---------------- ELL adjacency build ----------------
__global__ void build_ell(const int* __restrict__ src, const int* __restrict__ dst,
                          const void* __restrict__ w,
                          int* __restrict__ cnt, int2* __restrict__ ell,
                          const int* __restrict__ flag) {
  bool isf32 = (*flag) > 32;
  int e = blockIdx.x * blockDim.x + threadIdx.x;
  if (e >= EE) return;
  int d = dst[e];
  if ((unsigned)d >= NN) return;
  int p = atomicAdd(&cnt[d], 1);
  if (p >= CAP) return;
  int s = src[e];
  float wf = isf32 ? ((const float*)w)[e] : bf2f(((const unsigned short*)w)[e]);
  if ((unsigned)s >= NN) { s = 0; wf = 0.f; }
  union { float f; int i; } wv; wv.f = wf;
  ell[(size_t)d * CAP + p] = make_int2(s, wv.i);
}

// pad each row's slots to a multiple of 8 with zero-weight edges so the
// spmm loops need no tails and masked ELL loads read only valid lines
__global__ void pad_ell(const int* __restrict__ cnt, int2* __restrict__ ell) {
  int wave = threadIdx.x >> 6, lane = threadIdx.x & 63;
  int row = blockIdx.x * 4 + wave;
  if (row >= NN) return;
  int n = cnt[row];
  if (n > CAP) n = CAP;
  int padn = (n + 7) & ~7;
  if (lane >= n && lane < padn) ell[(size_t)row * CAP + lane] = make_int2(0, 0);
}

// ============ first GEMM pair: z = x@W0+b0, supp = x@W1 (K=256, 256 cols) ============
__global__ __launch_bounds__(256) void gemm_first(
    const unsigned short* __restrict__ A,    // xbf [N][256]
    const unsigned short* __restrict__ BT,   // [256][256]: rows 0-127=W0T, 128-255=W1T
    unsigned short* __restrict__ C0,         // zbuf [N][128]  (+bias)
    unsigned short* __restrict__ C1,         // supp [N][128]
    const unsigned short* __restrict__ bias) {
  __shared__ unsigned short As[64 * 256];    // 32KB, row stride 512B, swizzled
  int t = threadIdx.x;
  int wave = t >> 6, lane = t & 63;
  int q = lane >> 4, mn = lane & 15;
  int r0 = blockIdx.x * 64;

  #pragma unroll
  for (int cc = 0; cc < 8; ++cc) {
    int L = cc * 4096 + t * 16;
    int row = L >> 9;
    int colb = (L & 511) ^ ((row & 7) << 4);
    int gr = r0 + row; if (gr >= NN) gr = NN - 1;
    GLOAD_LDS16((const char*)A + (size_t)gr * 512 + colb, (char*)As + L);
  }
  __syncthreads();

  floatx4 acc[4][4];
  floatx4 zf = {0.f, 0.f, 0.f, 0.f};
  #pragma unroll
  for (int i = 0; i < 4; ++i)
    #pragma unroll
    for (int j = 0; j < 4; ++j) acc[i][j] = zf;

  #pragma unroll
  for (int ks = 0; ks < 8; ++ks) {
    bf16x8 fa[4], fb[4];
    #pragma unroll
    for (int i = 0; i < 4; ++i) {
      int row = i * 16 + mn;
      fa[i] = *(const bf16x8*)((const char*)As + row * 512 +
                               ((ks * 64 + q * 16) ^ ((row & 7) << 4)));
    }
    #pragma unroll
    for (int j = 0; j < 4; ++j)
      fb[j] = *(const bf16x8*)((const char*)BT +
                               (size_t)(wave * 64 + j * 16 + mn) * 512 + ks * 64 + q * 16);
    #pragma unroll
    for (int i = 0; i < 4; ++i)
      #pragma unroll
      for (int j = 0; j < 4; ++j)
        acc[i][j] = __builtin_amdgcn_mfma_f32_16x16x32_bf16(fa[i], fb[j], acc[i][j], 0, 0, 0);
  }

  #pragma unroll
  for (int j = 0; j < 4; ++j) {
    int col = wave * 64 + j * 16 + mn;
    bool is0 = col < 128;
    int ccol = is0 ? col : col - 128;
    unsigned short* Cp = is0 ? C0 : C1;
    float badd = is0 ? bf2f(bias[ccol]) : 0.f;
    #pragma unroll
    for (int i = 0; i < 4; ++i) {
      int rbase = r0 + i * 16 + q * 4;
      #pragma unroll
      for (int rr = 0; rr < 4; ++rr) {
        int row = rbase + rr;
        if (row < NN) Cp[(size_t)row * 128 + ccol] = f2bf(acc[i][j][rr] + badd);
      }
    }
  }
}

// ============ mid GEMM: supp[N,128] = x_l[N(,KCAT stride)][128] @ B ============
__global__ __launch_bounds__(256) void gemm_mid(
    const unsigned short* __restrict__ A,    // row stride KCAT
    const unsigned short* __restrict__ BT,   // [128][128]
    unsigned short* __restrict__ C) {        // supp [N][128]
  __shared__ unsigned short As[32 * 128];    // 8KB, row stride 256B, swizzled
  int t = threadIdx.x;
  int wave = t >> 6, lane = t & 63;
  int q = lane >> 4, mn = lane & 15;
  int r0 = blockIdx.x * 32;

  #pragma unroll
  for (int cc = 0; cc < 2; ++cc) {
    int L = cc * 4096 + t * 16;
    int row = L >> 8;
    int colb = (L & 255) ^ ((row & 7) << 4);
    int gr = r0 + row; if (gr >= NN) gr = NN - 1;
    GLOAD_LDS16((const char*)A + (size_t)gr * (KCAT * 2) + colb, (char*)As + L);
  }
  __syncthreads();

  floatx4 acc[2][2];
  floatx4 zf = {0.f, 0.f, 0.f, 0.f};
  #pragma unroll
  for (int i = 0; i < 2; ++i)
    #pragma unroll
    for (int j = 0; j < 2; ++j) acc[i][j] = zf;

  #pragma unroll
  for (int ks = 0; ks < 4; ++ks) {
    bf16x8 fa[2], fb[2];
    #pragma unroll
    for (int i = 0; i < 2; ++i) {
      int row = i * 16 + mn;
      fa[i] = *(const bf16x8*)((const char*)As + row * 256 +
                               ((ks * 64 + q * 16) ^ ((row & 7) << 4)));
    }
    #pragma unroll
    for (int j = 0; j < 2; ++j)
      fb[j] = *(const bf16x8*)((const char*)BT +
                               (size_t)(wave * 32 + j * 16 + mn) * 256 + ks * 64 + q * 16);
    #pragma unroll
    for (int i = 0; i < 2; ++i)
      #pragma unroll
      for (int j = 0; j < 2; ++j)
        acc[i][j] = __builtin_amdgcn_mfma_f32_16x16x32_bf16(fa[i], fb[j], acc[i][j], 0, 0, 0);
  }

  #pragma unroll
  for (int i = 0; i < 2; ++i) {
    int rbase = r0 + i * 16 + q * 4;
    #pragma unroll
    for (int j = 0; j < 2; ++j) {
      int col = wave * 32 + j * 16 + mn;
      #pragma unroll
      for (int rr = 0; rr < 4; ++rr) {
        int row = rbase + rr;
        if (row < NN) C[(size_t)row * 128 + col] = f2bf(acc[i][j][rr]);
      }
    }
  }
}

// ============ final GEMM: s15[N,40] = xcat[N,1792] @ W15 (fp32 out) ============
// Key fix vs round-2: B-fragment loads are issued BEFORE the next-chunk stage
// (pinned by compiler memory fences). vmcnt completes FIFO per wave, so this
// keeps the MFMA wait at vmcnt(4) (L1-hot B) while the HBM stage stays in
// flight under the whole compute phase; the only drain is the pre-barrier one.
__global__ __launch_bounds__(256) void gemm_cat3(
    const unsigned short* __restrict__ A,    // xcat [N][1792]
    const unsigned short* __restrict__ BT,   // [48][1792]
    float* __restrict__ C) {
  __shared__ unsigned short As[2][64 * 128]; // 2 x 16KB, row stride 256B, swizzled
  int t = threadIdx.x;
  int wave = t >> 6, lane = t & 63;
  int q = lane >> 4, mn = lane & 15;
  int r0 = blockIdx.x * 64;

  floatx4 acc[3];
  floatx4 zf = {0.f, 0.f, 0.f, 0.f};
  #pragma unroll
  for (int j = 0; j < 3; ++j) acc[j] = zf;

  const char* bbase[3];
  #pragma unroll
  for (int j = 0; j < 3; ++j)
    bbase[j] = (const char*)BT + (size_t)(j * 16 + mn) * 3584 + q * 16;

  auto stage = [&](int c) {
    #pragma unroll
    for (int cc = 0; cc < 4; ++cc) {
      int L = cc * 4096 + t * 16;
      int row = L >> 8;
      int colb = (L & 255) ^ ((row & 7) << 4);
      int gr = r0 + row; if (gr >= NN) gr = NN - 1;
      GLOAD_LDS16((const char*)A + (size_t)gr * 3584 + c * 256 + colb,
                  (char*)As[c & 1] + L);
    }
  };

  stage(0);
  __syncthreads();
  int rloc = wave * 16 + mn;
  int rsw = (rloc & 7) << 4;
  for (int c = 0; c < 14; ++c) {
    // B fragments for chunk c FIRST (oldest in vmcnt queue -> cheap waits)
    bf16x8 fb[3][4];
    #pragma unroll
    for (int ks = 0; ks < 4; ++ks)
      #pragma unroll
      for (int j = 0; j < 3; ++j)
        fb[j][ks] = *(const bf16x8*)(bbase[j] + c * 256 + ks * 64);
    asm volatile("" ::: "memory");
    if (c + 1 < 14) stage(c + 1);   // HBM loads fly under the MFMAs below
    asm volatile("" ::: "memory");
    const char* buf = (const char*)As[c & 1];
    #pragma unroll
    for (int ks = 0; ks < 4; ++ks) {
      bf16x8 fa = *(const bf16x8*)(buf + rloc * 256 + ((ks * 64 + q * 16) ^ rsw));
      #pragma unroll
      for (int j = 0; j < 3; ++j)
        acc[j] = __builtin_amdgcn_mfma_f32_16x16x32_bf16(fa, fb[j][ks], acc[j], 0, 0, 0);
    }
    if (c + 1 < 14) __syncthreads();
  }

  #pragma unroll
  for (int j = 0; j < 3; ++j) {
    int col = j * 16 + mn;
    if (col < NC) {
      #pragma unroll
      for (int rr = 0; rr < 4; ++rr) {
        int row = r0 + wave * 16 + q * 4 + rr;
        if (row < NN) C[(size_t)row * NC + col] = acc[j][rr];
      }
    }
  }
}

// ---------------- SPMM fused: out = relu(agg + b) + res ----------------
// One WAVE per row. ELL load exec-masked to the padded count (reads only the
// valid cache lines); gather loop runs exact 8-batches, software-pipelined
// (loads of batch k+1 in flight under FMAs of batch k).
__global__ __launch_bounds__(256) void spmm_layer(
    const unsigned short* __restrict__ support, const int* __restrict__ cnt,
    const int2* __restrict__ ell, const unsigned short* __restrict__ bias,
    const unsigned short* __restrict__ res, int res_stride,
    unsigned short* __restrict__ out, int out_stride) {
  int wave = threadIdx.x >> 6, lane = threadIdx.x & 63;
  int row = blockIdx.x * 4 + wave;
  if (row >= NN) return;
  int n = cnt[row];
  if (n > CAP) n = CAP;
  int padn = (n + 7) & ~7;
  int2 ev = make_int2(0, 0);
  if (lane < padn) ev = ell[(size_t)row * CAP + lane];
  uint32_t bw = *(const uint32_t*)(bias + 2 * lane);
  uint32_t rw = *(const uint32_t*)(res + (size_t)row * res_stride + 2 * lane);

  float a0 = 0.f, a1 = 0.f;
  uint32_t gA[8], gB[8];
  auto load8 = [&](uint32_t* g, int j0) {
    #pragma unroll
    for (int u = 0; u < 8; ++u) {
      int s = __shfl(ev.x, j0 + u);
      g[u] = *(const uint32_t*)(support + (size_t)s * DH + 2 * lane);
    }
  };
  auto fma8 = [&](const uint32_t* g, int j0) {
    #pragma unroll
    for (int u = 0; u < 8; ++u) {
      union { int i; float f; } wv; wv.i = __shfl(ev.y, j0 + u);
      a0 += wv.f * bf2f((unsigned short)(g[u] & 0xffff));
      a1 += wv.f * bf2f((unsigned short)(g[u] >> 16));
    }
  };
  if (padn > 0) {
    load8(gA, 0);
    int b = 0;
    for (;;) {
      if (8 * (b + 1) < padn) load8(gB, 8 * (b + 1));
      fma8(gA, 8 * b);
      ++b; if (8 * b >= padn) break;
      if (8 * (b + 1) < padn) load8(gA, 8 * (b + 1));
      fma8(gB, 8 * b);
      ++b; if (8 * b >= padn) break;
    }
  }

  float v0 = fmaxf(a0 + bf2f((unsigned short)(bw & 0xffff)), 0.f) +
             bf2f((unsigned short)(rw & 0xffff));
  float v1 = fmaxf(a1 + bf2f((unsigned short)(bw >> 16)), 0.f) +
             bf2f((unsigned short)(rw >> 16));
  uint32_t o = (uint32_t)f2bf(v0) | ((uint32_t)f2bf(v1) << 16);
  *(uint32_t*)(out + (size_t)row * out_stride + 2 * lane) = o;
}

// ---------------- final SPMM (d=40) + bias + log_softmax -> FP32 output ----------------
__global__ __launch_bounds__(256) void spmm_softmax_out(
    const float* __restrict__ s15, const int* __restrict__ cnt,
    const int2* __restrict__ ell, const unsigned short* __restrict__ bias,
    float* __restrict__ out) {
  int wave = threadIdx.x >> 6, lane = threadIdx.x & 63;
  int row = blockIdx.x * 4 + wave;
  if (row >= NN) return;
  int n = cnt[row];
  if (n > CAP) n = CAP;
  int padn = (n + 7) & ~7;
  int2 ev = make_int2(0, 0);
  if (lane < padn) ev = ell[(size_t)row * CAP + lane];
  int fl = lane < NC ? lane : NC - 1;  // keep all 64 lanes convergent for shfl
  float acc = 0.f;
  for (int j = 0; j < padn; j += 4) {
    float g[4];
    #pragma unroll
    for (int u = 0; u < 4; ++u) {
      int s = __shfl(ev.x, j + u);
      g[u] = s15[(size_t)s * NC + fl];
    }
    #pragma unroll
    for (int u = 0; u < 4; ++u) {
      union { int i; float f; } wv; wv.i = __shfl(ev.y, j + u);
      acc += wv.f * g[u];
    }
  }
  acc += bf2f(bias[fl]);
  float v = (lane < NC) ? acc : -3.0e38f;
  float m = v;
  #pragma unroll
  for (int off = 32; off > 0; off >>= 1) m = fmaxf(m, __shfl_xor(m, off));
  float e = (lane < NC) ? expf(v - m) : 0.f;
  float sum = e;
  #pragma unroll
  for (int off = 32; off > 0; off >>= 1) sum += __shfl_xor(sum, off);
  if (lane < NC) out[(size_t)row * NC + lane] = v - m - logf(sum);
}

extern "C" void kernel_launch(void* const* d_in, const int* in_sizes, int n_in,
                              void* d_out, int out_size, void* d_ws, size_t ws_size,
                              hipStream_t stream) {
  const void* x   = d_in[0];
  const int* esrc = (const int*)d_in[1];
  const int* edst = (const int*)d_in[2];
  const void* ew  = d_in[3];
  const void* W0  = d_in[4];
  const void* b0  = d_in[5];
  const void* W1  = d_in[6];
  const void* b1  = d_in[7];
  const void* Wm  = d_in[8];
  const void* bm  = d_in[9];
  const void* W15 = d_in[10];
  const void* b15 = d_in[11];
  float* out = (float*)d_out;   // reference output dtype = float32

  char* ws = (char*)d_ws;
  size_t off = 0;
  auto alloc = [&](size_t bytes) -> void* {
    void* p = ws + off;
    off = (off + bytes + 255) & ~(size_t)255;
    return p;
  };
  unsigned short* xcat = (unsigned short*)alloc((size_t)NN * KCAT * 2);  // x14|...|x1
  unsigned short* xbf  = (unsigned short*)alloc((size_t)NN * 256 * 2);
  unsigned short* supp = (unsigned short*)alloc((size_t)NN * DH * 2);
  unsigned short* zbuf = (unsigned short*)alloc((size_t)NN * DH * 2);
  float* s15           = (float*)alloc((size_t)NN * NC * 4);
  int* counts          = (int*)alloc((size_t)(NN + 1) * 4);  // [NN] = dtype wild count
  int2* ell            = (int2*)alloc((size_t)NN * CAP * 8);
  unsigned short* W01T = (unsigned short*)alloc((size_t)256 * 256 * 2);  // rows0-127=W0T,128-255=W1T
  unsigned short* WmT  = (unsigned short*)alloc((size_t)13 * 128 * 128 * 2);
  unsigned short* W15T = (unsigned short*)alloc((size_t)48 * 1792 * 2);
  unsigned short* bb   = (unsigned short*)alloc((size_t)(128 + 128 + 13 * 128 + 40) * 2);
  if (off > ws_size) return;  // signature: output stays zero
  int* flag = counts + NN;
  unsigned short* b0b  = bb;
  unsigned short* b1b  = bb + 128;
  unsigned short* bmb  = bb + 256;
  unsigned short* b15b = bb + 256 + 13 * 128;

  init_counts_detect<<<197, 256, 0, stream>>>(counts, (const unsigned short*)x);
  transpose_w<<<128, 256, 0, stream>>>(W0, W01T, 1, 256, 128, 128, flag);
  transpose_w<<<128, 256, 0, stream>>>(W1, W01T + 128 * 256, 1, 256, 128, 128, flag);
  transpose_w<<<832, 256, 0, stream>>>(Wm, WmT, 13, 128, 128, 128, flag);
  transpose_w<<<336, 256, 0, stream>>>(W15, W15T, 1, 1792, 40, 48, flag);
  convert_f4<<<2048, 256, 0, stream>>>(x, xbf, NN * 256 / 4, flag);
  convert_bias<<<8, 256, 0, stream>>>(b0, b1, bm, b15, bb, flag);
  build_ell<<<3125, 256, 0, stream>>>(esrc, edst, ew, counts, ell, flag);

  int gb64 = (NN + 63) / 64;   // 782
  int gb32 = (NN + 31) / 32;   // 1563
  int sb   = (NN + 3) / 4;     // 12500 (4 rows/block, wave per row)
  pad_ell<<<sb, 256, 0, stream>>>(counts, ell);
  gemm_first<<<gb64, 256, 0, stream>>>(xbf, W01T, zbuf, supp, b0b);
  spmm_layer<<<sb, 256, 0, stream>>>(supp, counts, ell, b1b, zbuf, DH,
                                     xcat + 13 * DH, KCAT);                  // x1
  for (int l = 0; l < 13; ++l) {
    gemm_mid<<<gb32, 256, 0, stream>>>(xcat + (13 - l) * DH,
                                       WmT + l * 128 * 128, supp);
    spmm_layer<<<sb, 256, 0, stream>>>(supp, counts, ell, bmb + l * DH,
                                       xcat + (13 - l) * DH, KCAT,
                                       xcat + (12 - l) * DH, KCAT);
  }
  gemm_cat3<<<gb64, 256, 0, stream>>>(xcat, W15T, s15);
  spmm_softmax_out<<<sb, 256, 0, stream>>>(s15, counts, ell, b15b, out);
}